// Round 4
// baseline (147.858 us; speedup 1.0000x reference)
//
#include <hip/hip_runtime.h>
#include <math.h>

// Neighborlist screening: gather -> diff -> norm -> (dummy & cutoff) mask.
// Round 4: same as R3 (8 pairs/thread MLP + non-temporal streaming) but with
// clang ext_vector_type for NT builtins (HIP_vector_type rejected).
//
// Outputs (flat float32 in d_out):
//   [0,   P)  : screened i0 as float (-1.0 if screened out)
//   [P,  2P)  : screened i1 as float
//   [2P, 3P)  : distances
//   [3P, 6P)  : diff_vectors, row-major [P][3]
#define CUTOFF_F 5.2f

typedef float f32x4 __attribute__((ext_vector_type(4)));
typedef int   i32x4 __attribute__((ext_vector_type(4)));

__global__ __launch_bounds__(256) void pack_atoms_kernel(
    const int*   __restrict__ species,   // [N]
    const float* __restrict__ coords,    // [N*3]
    f32x4*       __restrict__ atoms,     // [N] packed (x,y,z,flag)
    int N)
{
    const int n = blockIdx.x * blockDim.x + threadIdx.x;
    if (n >= N) return;
    f32x4 a;
    a.x = coords[3l*n]; a.y = coords[3l*n+1]; a.z = coords[3l*n+2];
    a.w = (species[n] == -1) ? -1.0f : 0.0f;
    atoms[n] = a;
}

__global__ __launch_bounds__(256) void nbr_screen8_kernel(
    const f32x4* __restrict__ atoms,     // [N] packed (x,y,z,flag)
    const int*   __restrict__ nbr,       // [2*P]
    const float* __restrict__ shift,     // [P*3]
    float*       __restrict__ out,       // [6*P]
    int P)
{
    const int t    = blockIdx.x * blockDim.x + threadIdx.x;
    const long base = (long)t * 8;
    if (base >= P) return;

    if (base + 8 <= P) {
        // ---- streamed inputs (no reuse): non-temporal ----
        const i32x4* n0p = reinterpret_cast<const i32x4*>(nbr + base);
        const i32x4* n1p = reinterpret_cast<const i32x4*>(nbr + (long)P + base);
        const i32x4 i0a = __builtin_nontemporal_load(n0p);
        const i32x4 i0b = __builtin_nontemporal_load(n0p + 1);
        const i32x4 i1a = __builtin_nontemporal_load(n1p);
        const i32x4 i1b = __builtin_nontemporal_load(n1p + 1);
        const f32x4* sv = reinterpret_cast<const f32x4*>(shift + base * 3);
        f32x4 s[6];
        #pragma unroll
        for (int q = 0; q < 6; ++q) s[q] = __builtin_nontemporal_load(sv + q);

        const int ia[8] = {i0a.x, i0a.y, i0a.z, i0a.w, i0b.x, i0b.y, i0b.z, i0b.w};
        const int ib[8] = {i1a.x, i1a.y, i1a.z, i1a.w, i1b.x, i1b.y, i1b.z, i1b.w};

        // Issue all 16 gathers up front (max MLP before any use).
        f32x4 A[8], B[8];
        #pragma unroll
        for (int k = 0; k < 8; ++k) { A[k] = atoms[ia[k]]; B[k] = atoms[ib[k]]; }

        const float shf[24] = {s[0].x, s[0].y, s[0].z, s[0].w,
                               s[1].x, s[1].y, s[1].z, s[1].w,
                               s[2].x, s[2].y, s[2].z, s[2].w,
                               s[3].x, s[3].y, s[3].z, s[3].w,
                               s[4].x, s[4].y, s[4].z, s[4].w,
                               s[5].x, s[5].y, s[5].z, s[5].w};

        float oi0[8], oi1[8], od[8], dv[24];
        #pragma unroll
        for (int k = 0; k < 8; ++k) {
            const bool valid = (A[k].w == 0.0f) & (B[k].w == 0.0f);
            // (c0 - c1) + shift, left-to-right like the reference
            const float dx = (A[k].x - B[k].x) + shf[3*k];
            const float dy = (A[k].y - B[k].y) + shf[3*k+1];
            const float dz = (A[k].z - B[k].z) + shf[3*k+2];
            // block fma contraction: must bit-match numpy (x*x + y*y) + z*z
            const float d2 = __fadd_rn(__fadd_rn(__fmul_rn(dx, dx),
                                                 __fmul_rn(dy, dy)),
                                       __fmul_rn(dz, dz));
            const float dist = (d2 > 0.0f) ? sqrtf(d2) : 0.0f;
            const bool keep = valid && (dist <= CUTOFF_F);
            oi0[k] = keep ? (float)ia[k] : -1.0f;
            oi1[k] = keep ? (float)ib[k] : -1.0f;
            od[k]  = keep ? dist : 0.0f;
            dv[3*k]   = keep ? dx : 0.0f;
            dv[3*k+1] = keep ? dy : 0.0f;
            dv[3*k+2] = keep ? dz : 0.0f;
        }

        // ---- streamed outputs: non-temporal (keep atoms in L2) ----
        f32x4* o0 = reinterpret_cast<f32x4*>(out + base);
        f32x4* o1 = reinterpret_cast<f32x4*>(out + (long)P + base);
        f32x4* o2 = reinterpret_cast<f32x4*>(out + 2l*P + base);
        f32x4* o3 = reinterpret_cast<f32x4*>(out + 3l*P + base*3);
        f32x4 v;
        v.x = oi0[0]; v.y = oi0[1]; v.z = oi0[2]; v.w = oi0[3];
        __builtin_nontemporal_store(v, o0);
        v.x = oi0[4]; v.y = oi0[5]; v.z = oi0[6]; v.w = oi0[7];
        __builtin_nontemporal_store(v, o0 + 1);
        v.x = oi1[0]; v.y = oi1[1]; v.z = oi1[2]; v.w = oi1[3];
        __builtin_nontemporal_store(v, o1);
        v.x = oi1[4]; v.y = oi1[5]; v.z = oi1[6]; v.w = oi1[7];
        __builtin_nontemporal_store(v, o1 + 1);
        v.x = od[0]; v.y = od[1]; v.z = od[2]; v.w = od[3];
        __builtin_nontemporal_store(v, o2);
        v.x = od[4]; v.y = od[5]; v.z = od[6]; v.w = od[7];
        __builtin_nontemporal_store(v, o2 + 1);
        #pragma unroll
        for (int q = 0; q < 6; ++q) {
            v.x = dv[4*q]; v.y = dv[4*q+1]; v.z = dv[4*q+2]; v.w = dv[4*q+3];
            __builtin_nontemporal_store(v, o3 + q);
        }
    } else {
        // ---- scalar tail (P % 8 != 0) ----
        for (long p = base; p < P; ++p) {
            const int a = nbr[p], b = nbr[(long)P + p];
            const f32x4 ca = atoms[a], cb = atoms[b];
            const bool valid = (ca.w == 0.0f) & (cb.w == 0.0f);
            const float dx = (ca.x - cb.x) + shift[p*3];
            const float dy = (ca.y - cb.y) + shift[p*3+1];
            const float dz = (ca.z - cb.z) + shift[p*3+2];
            const float d2 = __fadd_rn(__fadd_rn(__fmul_rn(dx, dx),
                                                 __fmul_rn(dy, dy)),
                                       __fmul_rn(dz, dz));
            const float dist = (d2 > 0.0f) ? sqrtf(d2) : 0.0f;
            const bool keep = valid && (dist <= CUTOFF_F);
            out[p]         = keep ? (float)a : -1.0f;
            out[(long)P+p] = keep ? (float)b : -1.0f;
            out[2l*P+p]    = keep ? dist : 0.0f;
            out[3l*P+p*3]   = keep ? dx : 0.0f;
            out[3l*P+p*3+1] = keep ? dy : 0.0f;
            out[3l*P+p*3+2] = keep ? dz : 0.0f;
        }
    }
}

extern "C" void kernel_launch(void* const* d_in, const int* in_sizes, int n_in,
                              void* d_out, int out_size, void* d_ws, size_t ws_size,
                              hipStream_t stream) {
    const int*   species = (const int*)  d_in[0];   // (1, N) int32
    const float* coords  = (const float*)d_in[1];   // (1, N, 3) f32
    const int*   nbr     = (const int*)  d_in[2];   // (2, P) int32
    const float* shift   = (const float*)d_in[3];   // (P, 3) f32
    float* out = (float*)d_out;                     // 6*P floats

    const int N = in_sizes[0];
    const int P = in_sizes[2] / 2;
    const int block = 256;

    f32x4* atoms = (f32x4*)d_ws;
    hipLaunchKernelGGL(pack_atoms_kernel, dim3((N + block - 1) / block),
                       dim3(block), 0, stream, species, coords, atoms, N);
    const int T = (P + 7) / 8;
    hipLaunchKernelGGL(nbr_screen8_kernel,
                       dim3((T + block - 1) / block), dim3(block), 0, stream,
                       atoms, nbr, shift, out, P);
}

// Round 5
// 98.495 us; speedup vs baseline: 1.5012x; 1.5012x over previous
//
#include <hip/hip_runtime.h>
#include <math.h>

// Neighborlist screening: gather -> diff -> norm -> (dummy & cutoff) mask.
// Round 5: fix the 48B-strided global access patterns (shift loads, dv stores)
// by staging through LDS so every global access is lane-unit-stride float4.
// NT stores reverted (they inflated WRITE_SIZE 150->227MB in R4).
//
// Outputs (flat float32 in d_out):
//   [0,   P)  : screened i0 as float (-1.0 if screened out)
//   [P,  2P)  : screened i1 as float
//   [2P, 3P)  : distances
//   [3P, 6P)  : diff_vectors, row-major [P][3]
#define CUTOFF_F 5.2f
#define BLOCK 256
#define PPT 4                 // pairs per thread
#define BP (BLOCK * PPT)      // 1024 pairs per block

typedef float f32x4 __attribute__((ext_vector_type(4)));
typedef int   i32x4 __attribute__((ext_vector_type(4)));

__global__ __launch_bounds__(BLOCK) void pack_atoms_kernel(
    const int*   __restrict__ species,   // [N]
    const float* __restrict__ coords,    // [N*3]
    f32x4*       __restrict__ atoms,     // [N] packed (x,y,z,flag)
    int N)
{
    const int n = blockIdx.x * blockDim.x + threadIdx.x;
    if (n >= N) return;
    f32x4 a;
    a.x = coords[3l*n]; a.y = coords[3l*n+1]; a.z = coords[3l*n+2];
    a.w = (species[n] == -1) ? -1.0f : 0.0f;
    atoms[n] = a;
}

__global__ __launch_bounds__(BLOCK) void nbr_screen_lds_kernel(
    const f32x4* __restrict__ atoms,     // [N] packed (x,y,z,flag)
    const int*   __restrict__ nbr,       // [2*P]
    const float* __restrict__ shift,     // [P*3]
    float*       __restrict__ out,       // [6*P]
    int P)
{
    __shared__ f32x4 lds[3 * BLOCK];     // 768 float4 = 12 KB (shift, then dv)
    const int  tid = threadIdx.x;
    const long PB  = (long)blockIdx.x * BP;

    if (PB + BP <= P) {
        // ---- phase 1: coop load shift[PB*3 .. PB*3+3*BP) unit-stride ----
        const f32x4* src = reinterpret_cast<const f32x4*>(shift + PB * 3);
        #pragma unroll
        for (int q = 0; q < 3; ++q)
            lds[q * BLOCK + tid] = src[q * BLOCK + tid];

        // ---- issue nbr loads + all 8 atom gathers before the barrier ----
        const long base = PB + (long)tid * PPT;
        const i32x4 i0v = *reinterpret_cast<const i32x4*>(nbr + base);
        const i32x4 i1v = *reinterpret_cast<const i32x4*>(nbr + (long)P + base);
        const int ia[4] = {i0v.x, i0v.y, i0v.z, i0v.w};
        const int ib[4] = {i1v.x, i1v.y, i1v.z, i1v.w};
        f32x4 A[4], B[4];
        #pragma unroll
        for (int k = 0; k < 4; ++k) { A[k] = atoms[ia[k]]; B[k] = atoms[ib[k]]; }

        __syncthreads();

        // ---- phase 2: per-thread strided read of shift from LDS ----
        const f32x4 s0 = lds[tid*3+0], s1 = lds[tid*3+1], s2 = lds[tid*3+2];
        const float shf[12] = {s0.x, s0.y, s0.z, s0.w,
                               s1.x, s1.y, s1.z, s1.w,
                               s2.x, s2.y, s2.z, s2.w};

        float oi0[4], oi1[4], od[4], dv[12];
        #pragma unroll
        for (int k = 0; k < 4; ++k) {
            const bool valid = (A[k].w == 0.0f) & (B[k].w == 0.0f);
            // (c0 - c1) + shift, left-to-right like the reference
            const float dx = (A[k].x - B[k].x) + shf[3*k];
            const float dy = (A[k].y - B[k].y) + shf[3*k+1];
            const float dz = (A[k].z - B[k].z) + shf[3*k+2];
            // block fma contraction: must bit-match numpy (x*x + y*y) + z*z
            const float d2 = __fadd_rn(__fadd_rn(__fmul_rn(dx, dx),
                                                 __fmul_rn(dy, dy)),
                                       __fmul_rn(dz, dz));
            const float dist = (d2 > 0.0f) ? sqrtf(d2) : 0.0f;
            const bool keep = valid && (dist <= CUTOFF_F);
            oi0[k] = keep ? (float)ia[k] : -1.0f;
            oi1[k] = keep ? (float)ib[k] : -1.0f;
            od[k]  = keep ? dist : 0.0f;
            dv[3*k]   = keep ? dx : 0.0f;
            dv[3*k+1] = keep ? dy : 0.0f;
            dv[3*k+2] = keep ? dz : 0.0f;
        }

        // ---- phase 3: dv into the same LDS slots this thread just read ----
        // (no barrier needed: each thread reads/writes only slots 3*tid..3*tid+2)
        f32x4 d0, d1, d2v;
        d0.x = dv[0];  d0.y = dv[1];  d0.z = dv[2];  d0.w = dv[3];
        d1.x = dv[4];  d1.y = dv[5];  d1.z = dv[6];  d1.w = dv[7];
        d2v.x = dv[8]; d2v.y = dv[9]; d2v.z = dv[10]; d2v.w = dv[11];
        lds[tid*3+0] = d0; lds[tid*3+1] = d1; lds[tid*3+2] = d2v;

        // ---- unit-stride stores for indices + distances ----
        f32x4 v;
        f32x4* o0 = reinterpret_cast<f32x4*>(out) + (base >> 2);
        f32x4* o1 = reinterpret_cast<f32x4*>(out + (long)P) + (base >> 2);
        f32x4* o2 = reinterpret_cast<f32x4*>(out + 2l*P) + (base >> 2);
        v.x = oi0[0]; v.y = oi0[1]; v.z = oi0[2]; v.w = oi0[3]; *o0 = v;
        v.x = oi1[0]; v.y = oi1[1]; v.z = oi1[2]; v.w = oi1[3]; *o1 = v;
        v.x = od[0];  v.y = od[1];  v.z = od[2];  v.w = od[3];  *o2 = v;

        __syncthreads();

        // ---- phase 4: coop store dv region unit-stride ----
        f32x4* dst = reinterpret_cast<f32x4*>(out + 3l*P + PB*3);
        #pragma unroll
        for (int q = 0; q < 3; ++q)
            dst[q * BLOCK + tid] = lds[q * BLOCK + tid];
    } else {
        // ---- scalar tail (partial block) ----
        for (long p = PB + tid; p < P; p += BLOCK) {
            const int a = nbr[p], b = nbr[(long)P + p];
            const f32x4 ca = atoms[a], cb = atoms[b];
            const bool valid = (ca.w == 0.0f) & (cb.w == 0.0f);
            const float dx = (ca.x - cb.x) + shift[p*3];
            const float dy = (ca.y - cb.y) + shift[p*3+1];
            const float dz = (ca.z - cb.z) + shift[p*3+2];
            const float d2 = __fadd_rn(__fadd_rn(__fmul_rn(dx, dx),
                                                 __fmul_rn(dy, dy)),
                                       __fmul_rn(dz, dz));
            const float dist = (d2 > 0.0f) ? sqrtf(d2) : 0.0f;
            const bool keep = valid && (dist <= CUTOFF_F);
            out[p]         = keep ? (float)a : -1.0f;
            out[(long)P+p] = keep ? (float)b : -1.0f;
            out[2l*P+p]    = keep ? dist : 0.0f;
            out[3l*P+p*3]   = keep ? dx : 0.0f;
            out[3l*P+p*3+1] = keep ? dy : 0.0f;
            out[3l*P+p*3+2] = keep ? dz : 0.0f;
        }
    }
}

extern "C" void kernel_launch(void* const* d_in, const int* in_sizes, int n_in,
                              void* d_out, int out_size, void* d_ws, size_t ws_size,
                              hipStream_t stream) {
    const int*   species = (const int*)  d_in[0];   // (1, N) int32
    const float* coords  = (const float*)d_in[1];   // (1, N, 3) f32
    const int*   nbr     = (const int*)  d_in[2];   // (2, P) int32
    const float* shift   = (const float*)d_in[3];   // (P, 3) f32
    float* out = (float*)d_out;                     // 6*P floats

    const int N = in_sizes[0];
    const int P = in_sizes[2] / 2;

    f32x4* atoms = (f32x4*)d_ws;
    hipLaunchKernelGGL(pack_atoms_kernel, dim3((N + BLOCK - 1) / BLOCK),
                       dim3(BLOCK), 0, stream, species, coords, atoms, N);
    const int grid = (P + BP - 1) / BP;
    hipLaunchKernelGGL(nbr_screen_lds_kernel, dim3(grid), dim3(BLOCK), 0,
                       stream, atoms, nbr, shift, out, P);
}

// Round 6
// 95.455 us; speedup vs baseline: 1.5490x; 1.0318x over previous
//
#include <hip/hip_runtime.h>
#include <math.h>

// Neighborlist screening: gather -> diff -> norm -> (dummy & cutoff) mask.
// Round 6: keep atoms array L2-resident by making ALL stream traffic
// non-temporal (no-allocate): NT loads for nbr/shift, NT stores for the
// unit-stride outputs (full-line coverage, so no R4-style write inflation).
// Also: issue nbr loads before shift loads before gathers to overlap latency.
//
// Outputs (flat float32 in d_out):
//   [0,   P)  : screened i0 as float (-1.0 if screened out)
//   [P,  2P)  : screened i1 as float
//   [2P, 3P)  : distances
//   [3P, 6P)  : diff_vectors, row-major [P][3]
#define CUTOFF_F 5.2f
#define BLOCK 256
#define PPT 4                 // pairs per thread
#define BP (BLOCK * PPT)      // 1024 pairs per block

typedef float f32x4 __attribute__((ext_vector_type(4)));
typedef int   i32x4 __attribute__((ext_vector_type(4)));

__global__ __launch_bounds__(BLOCK) void pack_atoms_kernel(
    const int*   __restrict__ species,   // [N]
    const float* __restrict__ coords,    // [N*3]
    f32x4*       __restrict__ atoms,     // [N] packed (x,y,z,flag)
    int N)
{
    const int n = blockIdx.x * blockDim.x + threadIdx.x;
    if (n >= N) return;
    f32x4 a;
    a.x = coords[3l*n]; a.y = coords[3l*n+1]; a.z = coords[3l*n+2];
    a.w = (species[n] == -1) ? -1.0f : 0.0f;
    atoms[n] = a;
}

__global__ __launch_bounds__(BLOCK) void nbr_screen_lds_kernel(
    const f32x4* __restrict__ atoms,     // [N] packed (x,y,z,flag)
    const int*   __restrict__ nbr,       // [2*P]
    const float* __restrict__ shift,     // [P*3]
    float*       __restrict__ out,       // [6*P]
    int P)
{
    __shared__ f32x4 lds[3 * BLOCK];     // 768 float4 = 12 KB (shift, then dv)
    const int  tid = threadIdx.x;
    const long PB  = (long)blockIdx.x * BP;

    if (PB + BP <= P) {
        // ---- issue order: nbr (needed for gather addrs) -> shift -> gathers
        const long base = PB + (long)tid * PPT;
        const i32x4 i0v = __builtin_nontemporal_load(
            reinterpret_cast<const i32x4*>(nbr + base));
        const i32x4 i1v = __builtin_nontemporal_load(
            reinterpret_cast<const i32x4*>(nbr + (long)P + base));

        const f32x4* src = reinterpret_cast<const f32x4*>(shift + PB * 3);
        f32x4 sreg[3];
        #pragma unroll
        for (int q = 0; q < 3; ++q)
            sreg[q] = __builtin_nontemporal_load(src + q * BLOCK + tid);

        const int ia[4] = {i0v.x, i0v.y, i0v.z, i0v.w};
        const int ib[4] = {i1v.x, i1v.y, i1v.z, i1v.w};
        // atom gathers: REGULAR loads (we want these cached in L2)
        f32x4 A[4], B[4];
        #pragma unroll
        for (int k = 0; k < 4; ++k) { A[k] = atoms[ia[k]]; B[k] = atoms[ib[k]]; }

        // stage shift into LDS (transpose unit-stride -> per-pair order)
        #pragma unroll
        for (int q = 0; q < 3; ++q)
            lds[q * BLOCK + tid] = sreg[q];
        __syncthreads();

        const f32x4 s0 = lds[tid*3+0], s1 = lds[tid*3+1], s2 = lds[tid*3+2];
        const float shf[12] = {s0.x, s0.y, s0.z, s0.w,
                               s1.x, s1.y, s1.z, s1.w,
                               s2.x, s2.y, s2.z, s2.w};

        float oi0[4], oi1[4], od[4], dv[12];
        #pragma unroll
        for (int k = 0; k < 4; ++k) {
            const bool valid = (A[k].w == 0.0f) & (B[k].w == 0.0f);
            // (c0 - c1) + shift, left-to-right like the reference
            const float dx = (A[k].x - B[k].x) + shf[3*k];
            const float dy = (A[k].y - B[k].y) + shf[3*k+1];
            const float dz = (A[k].z - B[k].z) + shf[3*k+2];
            // block fma contraction: must bit-match numpy (x*x + y*y) + z*z
            const float d2 = __fadd_rn(__fadd_rn(__fmul_rn(dx, dx),
                                                 __fmul_rn(dy, dy)),
                                       __fmul_rn(dz, dz));
            const float dist = (d2 > 0.0f) ? sqrtf(d2) : 0.0f;
            const bool keep = valid && (dist <= CUTOFF_F);
            oi0[k] = keep ? (float)ia[k] : -1.0f;
            oi1[k] = keep ? (float)ib[k] : -1.0f;
            od[k]  = keep ? dist : 0.0f;
            dv[3*k]   = keep ? dx : 0.0f;
            dv[3*k+1] = keep ? dy : 0.0f;
            dv[3*k+2] = keep ? dz : 0.0f;
        }

        // dv into the same LDS slots this thread just read
        // (no barrier needed: each thread reads/writes only slots 3*tid..3*tid+2)
        f32x4 d0, d1, d2v;
        d0.x = dv[0];  d0.y = dv[1];  d0.z = dv[2];  d0.w = dv[3];
        d1.x = dv[4];  d1.y = dv[5];  d1.z = dv[6];  d1.w = dv[7];
        d2v.x = dv[8]; d2v.y = dv[9]; d2v.z = dv[10]; d2v.w = dv[11];
        lds[tid*3+0] = d0; lds[tid*3+1] = d1; lds[tid*3+2] = d2v;

        // unit-stride NT stores for indices + distances
        f32x4 v;
        f32x4* o0 = reinterpret_cast<f32x4*>(out) + (base >> 2);
        f32x4* o1 = reinterpret_cast<f32x4*>(out + (long)P) + (base >> 2);
        f32x4* o2 = reinterpret_cast<f32x4*>(out + 2l*P) + (base >> 2);
        v.x = oi0[0]; v.y = oi0[1]; v.z = oi0[2]; v.w = oi0[3];
        __builtin_nontemporal_store(v, o0);
        v.x = oi1[0]; v.y = oi1[1]; v.z = oi1[2]; v.w = oi1[3];
        __builtin_nontemporal_store(v, o1);
        v.x = od[0];  v.y = od[1];  v.z = od[2];  v.w = od[3];
        __builtin_nontemporal_store(v, o2);

        __syncthreads();

        // coop store dv region unit-stride (full-line NT stores)
        f32x4* dst = reinterpret_cast<f32x4*>(out + 3l*P + PB*3);
        #pragma unroll
        for (int q = 0; q < 3; ++q)
            __builtin_nontemporal_store(lds[q * BLOCK + tid],
                                        dst + q * BLOCK + tid);
    } else {
        // ---- scalar tail (partial block) ----
        for (long p = PB + tid; p < P; p += BLOCK) {
            const int a = nbr[p], b = nbr[(long)P + p];
            const f32x4 ca = atoms[a], cb = atoms[b];
            const bool valid = (ca.w == 0.0f) & (cb.w == 0.0f);
            const float dx = (ca.x - cb.x) + shift[p*3];
            const float dy = (ca.y - cb.y) + shift[p*3+1];
            const float dz = (ca.z - cb.z) + shift[p*3+2];
            const float d2 = __fadd_rn(__fadd_rn(__fmul_rn(dx, dx),
                                                 __fmul_rn(dy, dy)),
                                       __fmul_rn(dz, dz));
            const float dist = (d2 > 0.0f) ? sqrtf(d2) : 0.0f;
            const bool keep = valid && (dist <= CUTOFF_F);
            out[p]         = keep ? (float)a : -1.0f;
            out[(long)P+p] = keep ? (float)b : -1.0f;
            out[2l*P+p]    = keep ? dist : 0.0f;
            out[3l*P+p*3]   = keep ? dx : 0.0f;
            out[3l*P+p*3+1] = keep ? dy : 0.0f;
            out[3l*P+p*3+2] = keep ? dz : 0.0f;
        }
    }
}

extern "C" void kernel_launch(void* const* d_in, const int* in_sizes, int n_in,
                              void* d_out, int out_size, void* d_ws, size_t ws_size,
                              hipStream_t stream) {
    const int*   species = (const int*)  d_in[0];   // (1, N) int32
    const float* coords  = (const float*)d_in[1];   // (1, N, 3) f32
    const int*   nbr     = (const int*)  d_in[2];   // (2, P) int32
    const float* shift   = (const float*)d_in[3];   // (P, 3) f32
    float* out = (float*)d_out;                     // 6*P floats

    const int N = in_sizes[0];
    const int P = in_sizes[2] / 2;

    f32x4* atoms = (f32x4*)d_ws;
    hipLaunchKernelGGL(pack_atoms_kernel, dim3((N + BLOCK - 1) / BLOCK),
                       dim3(BLOCK), 0, stream, species, coords, atoms, N);
    const int grid = (P + BP - 1) / BP;
    hipLaunchKernelGGL(nbr_screen_lds_kernel, dim3(grid), dim3(BLOCK), 0,
                       stream, atoms, nbr, shift, out, P);
}

// Round 7
// 93.273 us; speedup vs baseline: 1.5852x; 1.0234x over previous
//
#include <hip/hip_runtime.h>
#include <math.h>

// Neighborlist screening: gather -> diff -> norm -> (dummy & cutoff) mask.
// Round 7: R6 structure (LDS-staged strided streams + NT stream traffic)
// with PPT=8 as two 4-pair chunks -> 16 atom gathers in flight per wave
// (2x MLP; gather-throughput = waves x outstanding / latency).
//
// Outputs (flat float32 in d_out):
//   [0,   P)  : screened i0 as float (-1.0 if screened out)
//   [P,  2P)  : screened i1 as float
//   [2P, 3P)  : distances
//   [3P, 6P)  : diff_vectors, row-major [P][3]
#define CUTOFF_F 5.2f
#define BLOCK 256
#define PPT 8                 // pairs per thread (two chunks of 4)
#define BP (BLOCK * PPT)      // 2048 pairs per block

typedef float f32x4 __attribute__((ext_vector_type(4)));
typedef int   i32x4 __attribute__((ext_vector_type(4)));

__global__ __launch_bounds__(BLOCK) void pack_atoms_kernel(
    const int*   __restrict__ species,   // [N]
    const float* __restrict__ coords,    // [N*3]
    f32x4*       __restrict__ atoms,     // [N] packed (x,y,z,flag)
    int N)
{
    const int n = blockIdx.x * blockDim.x + threadIdx.x;
    if (n >= N) return;
    f32x4 a;
    a.x = coords[3l*n]; a.y = coords[3l*n+1]; a.z = coords[3l*n+2];
    a.w = (species[n] == -1) ? -1.0f : 0.0f;
    atoms[n] = a;
}

__global__ __launch_bounds__(BLOCK) void nbr_screen8_lds_kernel(
    const f32x4* __restrict__ atoms,     // [N] packed (x,y,z,flag)
    const int*   __restrict__ nbr,       // [2*P]
    const float* __restrict__ shift,     // [P*3]
    float*       __restrict__ out,       // [6*P]
    int P)
{
    __shared__ f32x4 lds[6 * BLOCK];     // 1536 float4 = 24 KB (shift, then dv)
    const int  tid = threadIdx.x;
    const long PB  = (long)blockIdx.x * BP;

    if (PB + BP <= P) {
        const long baseA = PB + (long)tid * 4;          // chunk A: 4 pairs
        const long baseB = baseA + (long)BLOCK * 4;     // chunk B: 4 pairs

        // ---- issue order: nbr (gather addrs) -> shift -> all 16 gathers ----
        const i32x4 i0A = __builtin_nontemporal_load(
            reinterpret_cast<const i32x4*>(nbr + baseA));
        const i32x4 i1A = __builtin_nontemporal_load(
            reinterpret_cast<const i32x4*>(nbr + (long)P + baseA));
        const i32x4 i0B = __builtin_nontemporal_load(
            reinterpret_cast<const i32x4*>(nbr + baseB));
        const i32x4 i1B = __builtin_nontemporal_load(
            reinterpret_cast<const i32x4*>(nbr + (long)P + baseB));

        const f32x4* src = reinterpret_cast<const f32x4*>(shift + PB * 3);
        f32x4 sreg[6];
        #pragma unroll
        for (int q = 0; q < 6; ++q)
            sreg[q] = __builtin_nontemporal_load(src + q * BLOCK + tid);

        const int ia[8] = {i0A.x, i0A.y, i0A.z, i0A.w, i0B.x, i0B.y, i0B.z, i0B.w};
        const int ib[8] = {i1A.x, i1A.y, i1A.z, i1A.w, i1B.x, i1B.y, i1B.z, i1B.w};
        // atom gathers: REGULAR loads (we want these cached in L2)
        f32x4 A[8], B[8];
        #pragma unroll
        for (int k = 0; k < 8; ++k) { A[k] = atoms[ia[k]]; B[k] = atoms[ib[k]]; }

        // stage shift into LDS (coalesced layout = natural contiguous order)
        #pragma unroll
        for (int q = 0; q < 6; ++q)
            lds[q * BLOCK + tid] = sreg[q];
        __syncthreads();

        // chunk A shifts: float4 idx tid*3 + {0,1,2}; chunk B: 3*BLOCK + tid*3 + {0,1,2}
        const f32x4 sA0 = lds[tid*3+0], sA1 = lds[tid*3+1], sA2 = lds[tid*3+2];
        const f32x4 sB0 = lds[3*BLOCK + tid*3+0], sB1 = lds[3*BLOCK + tid*3+1],
                    sB2 = lds[3*BLOCK + tid*3+2];
        const float shf[24] = {sA0.x, sA0.y, sA0.z, sA0.w,
                               sA1.x, sA1.y, sA1.z, sA1.w,
                               sA2.x, sA2.y, sA2.z, sA2.w,
                               sB0.x, sB0.y, sB0.z, sB0.w,
                               sB1.x, sB1.y, sB1.z, sB1.w,
                               sB2.x, sB2.y, sB2.z, sB2.w};

        float oi0[8], oi1[8], od[8], dv[24];
        #pragma unroll
        for (int k = 0; k < 8; ++k) {
            const bool valid = (A[k].w == 0.0f) & (B[k].w == 0.0f);
            // (c0 - c1) + shift, left-to-right like the reference
            const float dx = (A[k].x - B[k].x) + shf[3*k];
            const float dy = (A[k].y - B[k].y) + shf[3*k+1];
            const float dz = (A[k].z - B[k].z) + shf[3*k+2];
            // block fma contraction: must bit-match numpy (x*x + y*y) + z*z
            const float d2 = __fadd_rn(__fadd_rn(__fmul_rn(dx, dx),
                                                 __fmul_rn(dy, dy)),
                                       __fmul_rn(dz, dz));
            const float dist = (d2 > 0.0f) ? sqrtf(d2) : 0.0f;
            const bool keep = valid && (dist <= CUTOFF_F);
            oi0[k] = keep ? (float)ia[k] : -1.0f;
            oi1[k] = keep ? (float)ib[k] : -1.0f;
            od[k]  = keep ? dist : 0.0f;
            dv[3*k]   = keep ? dx : 0.0f;
            dv[3*k+1] = keep ? dy : 0.0f;
            dv[3*k+2] = keep ? dz : 0.0f;
        }

        // dv into the same LDS slots each thread just read (no barrier needed)
        f32x4 w;
        w.x = dv[0];  w.y = dv[1];  w.z = dv[2];  w.w = dv[3];  lds[tid*3+0] = w;
        w.x = dv[4];  w.y = dv[5];  w.z = dv[6];  w.w = dv[7];  lds[tid*3+1] = w;
        w.x = dv[8];  w.y = dv[9];  w.z = dv[10]; w.w = dv[11]; lds[tid*3+2] = w;
        w.x = dv[12]; w.y = dv[13]; w.z = dv[14]; w.w = dv[15]; lds[3*BLOCK + tid*3+0] = w;
        w.x = dv[16]; w.y = dv[17]; w.z = dv[18]; w.w = dv[19]; lds[3*BLOCK + tid*3+1] = w;
        w.x = dv[20]; w.y = dv[21]; w.z = dv[22]; w.w = dv[23]; lds[3*BLOCK + tid*3+2] = w;

        // unit-stride NT stores for indices + distances (both chunks)
        f32x4 v;
        f32x4* o0 = reinterpret_cast<f32x4*>(out);
        f32x4* o1 = reinterpret_cast<f32x4*>(out + (long)P);
        f32x4* o2 = reinterpret_cast<f32x4*>(out + 2l*P);
        v.x = oi0[0]; v.y = oi0[1]; v.z = oi0[2]; v.w = oi0[3];
        __builtin_nontemporal_store(v, o0 + (baseA >> 2));
        v.x = oi0[4]; v.y = oi0[5]; v.z = oi0[6]; v.w = oi0[7];
        __builtin_nontemporal_store(v, o0 + (baseB >> 2));
        v.x = oi1[0]; v.y = oi1[1]; v.z = oi1[2]; v.w = oi1[3];
        __builtin_nontemporal_store(v, o1 + (baseA >> 2));
        v.x = oi1[4]; v.y = oi1[5]; v.z = oi1[6]; v.w = oi1[7];
        __builtin_nontemporal_store(v, o1 + (baseB >> 2));
        v.x = od[0];  v.y = od[1];  v.z = od[2];  v.w = od[3];
        __builtin_nontemporal_store(v, o2 + (baseA >> 2));
        v.x = od[4];  v.y = od[5];  v.z = od[6];  v.w = od[7];
        __builtin_nontemporal_store(v, o2 + (baseB >> 2));

        __syncthreads();

        // coop store dv region unit-stride (full-line NT stores)
        f32x4* dst = reinterpret_cast<f32x4*>(out + 3l*P + PB*3);
        #pragma unroll
        for (int q = 0; q < 6; ++q)
            __builtin_nontemporal_store(lds[q * BLOCK + tid],
                                        dst + q * BLOCK + tid);
    } else {
        // ---- scalar tail (partial block) ----
        for (long p = PB + tid; p < P; p += BLOCK) {
            const int a = nbr[p], b = nbr[(long)P + p];
            const f32x4 ca = atoms[a], cb = atoms[b];
            const bool valid = (ca.w == 0.0f) & (cb.w == 0.0f);
            const float dx = (ca.x - cb.x) + shift[p*3];
            const float dy = (ca.y - cb.y) + shift[p*3+1];
            const float dz = (ca.z - cb.z) + shift[p*3+2];
            const float d2 = __fadd_rn(__fadd_rn(__fmul_rn(dx, dx),
                                                 __fmul_rn(dy, dy)),
                                       __fmul_rn(dz, dz));
            const float dist = (d2 > 0.0f) ? sqrtf(d2) : 0.0f;
            const bool keep = valid && (dist <= CUTOFF_F);
            out[p]         = keep ? (float)a : -1.0f;
            out[(long)P+p] = keep ? (float)b : -1.0f;
            out[2l*P+p]    = keep ? dist : 0.0f;
            out[3l*P+p*3]   = keep ? dx : 0.0f;
            out[3l*P+p*3+1] = keep ? dy : 0.0f;
            out[3l*P+p*3+2] = keep ? dz : 0.0f;
        }
    }
}

extern "C" void kernel_launch(void* const* d_in, const int* in_sizes, int n_in,
                              void* d_out, int out_size, void* d_ws, size_t ws_size,
                              hipStream_t stream) {
    const int*   species = (const int*)  d_in[0];   // (1, N) int32
    const float* coords  = (const float*)d_in[1];   // (1, N, 3) f32
    const int*   nbr     = (const int*)  d_in[2];   // (2, P) int32
    const float* shift   = (const float*)d_in[3];   // (P, 3) f32
    float* out = (float*)d_out;                     // 6*P floats

    const int N = in_sizes[0];
    const int P = in_sizes[2] / 2;

    f32x4* atoms = (f32x4*)d_ws;
    hipLaunchKernelGGL(pack_atoms_kernel, dim3((N + BLOCK - 1) / BLOCK),
                       dim3(BLOCK), 0, stream, species, coords, atoms, N);
    const int grid = (P + BP - 1) / BP;
    hipLaunchKernelGGL(nbr_screen8_lds_kernel, dim3(grid), dim3(BLOCK), 0,
                       stream, atoms, nbr, shift, out, P);
}

// Round 8
// 93.141 us; speedup vs baseline: 1.5875x; 1.0014x over previous
//
#include <hip/hip_runtime.h>
#include <math.h>

// Neighborlist screening: gather -> diff -> norm -> (dummy & cutoff) mask.
// Round 8: persistent software-pipelined kernel. Each block loops over tiles
// (stride = gridDim); nbr indices for the NEXT tile are prefetched while the
// current tile's 16 atom gathers are in flight -> removes the serial
// nbr-load -> gather-issue stall and raises average outstanding gathers.
// Keeps R6/R7 wins: LDS-staged 48B-strided streams, NT on all stream traffic.
//
// Outputs (flat float32 in d_out):
//   [0,   P)  : screened i0 as float (-1.0 if screened out)
//   [P,  2P)  : screened i1 as float
//   [2P, 3P)  : distances
//   [3P, 6P)  : diff_vectors, row-major [P][3]
#define CUTOFF_F 5.2f
#define BLOCK 256
#define PPT 8                 // pairs per thread (two chunks of 4)
#define BP (BLOCK * PPT)      // 2048 pairs per tile

typedef float f32x4 __attribute__((ext_vector_type(4)));
typedef int   i32x4 __attribute__((ext_vector_type(4)));

__global__ __launch_bounds__(BLOCK) void pack_atoms_kernel(
    const int*   __restrict__ species,   // [N]
    const float* __restrict__ coords,    // [N*3]
    f32x4*       __restrict__ atoms,     // [N] packed (x,y,z,flag)
    int N)
{
    const int n = blockIdx.x * blockDim.x + threadIdx.x;
    if (n >= N) return;
    f32x4 a;
    a.x = coords[3l*n]; a.y = coords[3l*n+1]; a.z = coords[3l*n+2];
    a.w = (species[n] == -1) ? -1.0f : 0.0f;
    atoms[n] = a;
}

__global__ __launch_bounds__(BLOCK) void nbr_screen_pipe_kernel(
    const f32x4* __restrict__ atoms,     // [N] packed (x,y,z,flag)
    const int*   __restrict__ nbr,       // [2*P]
    const float* __restrict__ shift,     // [P*3]
    float*       __restrict__ out,       // [6*P]
    int P)
{
    __shared__ f32x4 lds[6 * BLOCK];     // 1536 float4 = 24 KB (shift, then dv)
    const int tid    = threadIdx.x;
    const int nTiles = (P + BP - 1) / BP;
    const int t0     = blockIdx.x;
    if (t0 >= nTiles) return;

    // ---- prologue: load nbr indices for this block's first tile ----
    i32x4 c0A, c1A, c0B, c1B;
    {
        const long PB = (long)t0 * BP;
        if (PB + BP <= P) {
            const long baseA = PB + (long)tid * 4;
            const long baseB = baseA + (long)BLOCK * 4;
            c0A = __builtin_nontemporal_load(reinterpret_cast<const i32x4*>(nbr + baseA));
            c1A = __builtin_nontemporal_load(reinterpret_cast<const i32x4*>(nbr + (long)P + baseA));
            c0B = __builtin_nontemporal_load(reinterpret_cast<const i32x4*>(nbr + baseB));
            c1B = __builtin_nontemporal_load(reinterpret_cast<const i32x4*>(nbr + (long)P + baseB));
        }
    }

    for (int t = t0; t < nTiles; t += gridDim.x) {
        const long PB = (long)t * BP;
        if (PB + BP <= P) {
            const long baseA = PB + (long)tid * 4;
            const long baseB = baseA + (long)BLOCK * 4;

            const int ia[8] = {c0A.x, c0A.y, c0A.z, c0A.w, c0B.x, c0B.y, c0B.z, c0B.w};
            const int ib[8] = {c1A.x, c1A.y, c1A.z, c1A.w, c1B.x, c1B.y, c1B.z, c1B.w};

            // ---- issue all 16 atom gathers FIRST (addresses already resident)
            f32x4 A[8], B[8];
            #pragma unroll
            for (int k = 0; k < 8; ++k) { A[k] = atoms[ia[k]]; B[k] = atoms[ib[k]]; }

            // ---- shift loads for this tile (latency hides under gathers) ----
            const f32x4* src = reinterpret_cast<const f32x4*>(shift + PB * 3);
            f32x4 sreg[6];
            #pragma unroll
            for (int q = 0; q < 6; ++q)
                sreg[q] = __builtin_nontemporal_load(src + q * BLOCK + tid);

            // ---- prefetch next tile's nbr indices (needed ~1 iter later) ----
            const int  tn   = t + gridDim.x;
            const long PBn  = (long)tn * BP;
            i32x4 n0A, n1A, n0B, n1B;
            const bool pre = (PBn + BP <= P);
            if (pre) {
                const long bA = PBn + (long)tid * 4;
                const long bB = bA + (long)BLOCK * 4;
                n0A = __builtin_nontemporal_load(reinterpret_cast<const i32x4*>(nbr + bA));
                n1A = __builtin_nontemporal_load(reinterpret_cast<const i32x4*>(nbr + (long)P + bA));
                n0B = __builtin_nontemporal_load(reinterpret_cast<const i32x4*>(nbr + bB));
                n1B = __builtin_nontemporal_load(reinterpret_cast<const i32x4*>(nbr + (long)P + bB));
            }

            // ---- stage shift into LDS (linear layout; same slots this thread
            //      will later reuse for dv -> no extra barrier vs prev iter) ----
            #pragma unroll
            for (int q = 0; q < 6; ++q)
                lds[q * BLOCK + tid] = sreg[q];
            __syncthreads();

            const f32x4 sA0 = lds[tid*3+0], sA1 = lds[tid*3+1], sA2 = lds[tid*3+2];
            const f32x4 sB0 = lds[3*BLOCK + tid*3+0], sB1 = lds[3*BLOCK + tid*3+1],
                        sB2 = lds[3*BLOCK + tid*3+2];
            const float shf[24] = {sA0.x, sA0.y, sA0.z, sA0.w,
                                   sA1.x, sA1.y, sA1.z, sA1.w,
                                   sA2.x, sA2.y, sA2.z, sA2.w,
                                   sB0.x, sB0.y, sB0.z, sB0.w,
                                   sB1.x, sB1.y, sB1.z, sB1.w,
                                   sB2.x, sB2.y, sB2.z, sB2.w};

            float oi0[8], oi1[8], od[8], dv[24];
            #pragma unroll
            for (int k = 0; k < 8; ++k) {
                const bool valid = (A[k].w == 0.0f) & (B[k].w == 0.0f);
                // (c0 - c1) + shift, left-to-right like the reference
                const float dx = (A[k].x - B[k].x) + shf[3*k];
                const float dy = (A[k].y - B[k].y) + shf[3*k+1];
                const float dz = (A[k].z - B[k].z) + shf[3*k+2];
                // block fma contraction: bit-match numpy (x*x + y*y) + z*z
                const float d2 = __fadd_rn(__fadd_rn(__fmul_rn(dx, dx),
                                                     __fmul_rn(dy, dy)),
                                           __fmul_rn(dz, dz));
                const float dist = (d2 > 0.0f) ? sqrtf(d2) : 0.0f;
                const bool keep = valid && (dist <= CUTOFF_F);
                oi0[k] = keep ? (float)ia[k] : -1.0f;
                oi1[k] = keep ? (float)ib[k] : -1.0f;
                od[k]  = keep ? dist : 0.0f;
                dv[3*k]   = keep ? dx : 0.0f;
                dv[3*k+1] = keep ? dy : 0.0f;
                dv[3*k+2] = keep ? dz : 0.0f;
            }

            // dv into the same LDS slots each thread just read (no barrier)
            f32x4 w;
            w.x = dv[0];  w.y = dv[1];  w.z = dv[2];  w.w = dv[3];  lds[tid*3+0] = w;
            w.x = dv[4];  w.y = dv[5];  w.z = dv[6];  w.w = dv[7];  lds[tid*3+1] = w;
            w.x = dv[8];  w.y = dv[9];  w.z = dv[10]; w.w = dv[11]; lds[tid*3+2] = w;
            w.x = dv[12]; w.y = dv[13]; w.z = dv[14]; w.w = dv[15]; lds[3*BLOCK + tid*3+0] = w;
            w.x = dv[16]; w.y = dv[17]; w.z = dv[18]; w.w = dv[19]; lds[3*BLOCK + tid*3+1] = w;
            w.x = dv[20]; w.y = dv[21]; w.z = dv[22]; w.w = dv[23]; lds[3*BLOCK + tid*3+2] = w;

            // unit-stride NT stores for indices + distances (both chunks)
            f32x4 v;
            f32x4* o0 = reinterpret_cast<f32x4*>(out);
            f32x4* o1 = reinterpret_cast<f32x4*>(out + (long)P);
            f32x4* o2 = reinterpret_cast<f32x4*>(out + 2l*P);
            v.x = oi0[0]; v.y = oi0[1]; v.z = oi0[2]; v.w = oi0[3];
            __builtin_nontemporal_store(v, o0 + (baseA >> 2));
            v.x = oi0[4]; v.y = oi0[5]; v.z = oi0[6]; v.w = oi0[7];
            __builtin_nontemporal_store(v, o0 + (baseB >> 2));
            v.x = oi1[0]; v.y = oi1[1]; v.z = oi1[2]; v.w = oi1[3];
            __builtin_nontemporal_store(v, o1 + (baseA >> 2));
            v.x = oi1[4]; v.y = oi1[5]; v.z = oi1[6]; v.w = oi1[7];
            __builtin_nontemporal_store(v, o1 + (baseB >> 2));
            v.x = od[0];  v.y = od[1];  v.z = od[2];  v.w = od[3];
            __builtin_nontemporal_store(v, o2 + (baseA >> 2));
            v.x = od[4];  v.y = od[5];  v.z = od[6];  v.w = od[7];
            __builtin_nontemporal_store(v, o2 + (baseB >> 2));

            __syncthreads();

            // coop store dv region unit-stride (full-line NT stores).
            // Thread t reads exactly slots q*BLOCK+t, which it alone rewrites
            // next iteration -> no extra barrier at loop boundary.
            f32x4* dst = reinterpret_cast<f32x4*>(out + 3l*P + PB*3);
            #pragma unroll
            for (int q = 0; q < 6; ++q)
                __builtin_nontemporal_store(lds[q * BLOCK + tid],
                                            dst + q * BLOCK + tid);

            if (pre) { c0A = n0A; c1A = n1A; c0B = n0B; c1B = n1B; }
        } else {
            // ---- scalar tail (partial tile) ----
            for (long p = PB + tid; p < P; p += BLOCK) {
                const int a = nbr[p], b = nbr[(long)P + p];
                const f32x4 ca = atoms[a], cb = atoms[b];
                const bool valid = (ca.w == 0.0f) & (cb.w == 0.0f);
                const float dx = (ca.x - cb.x) + shift[p*3];
                const float dy = (ca.y - cb.y) + shift[p*3+1];
                const float dz = (ca.z - cb.z) + shift[p*3+2];
                const float d2 = __fadd_rn(__fadd_rn(__fmul_rn(dx, dx),
                                                     __fmul_rn(dy, dy)),
                                           __fmul_rn(dz, dz));
                const float dist = (d2 > 0.0f) ? sqrtf(d2) : 0.0f;
                const bool keep = valid && (dist <= CUTOFF_F);
                out[p]         = keep ? (float)a : -1.0f;
                out[(long)P+p] = keep ? (float)b : -1.0f;
                out[2l*P+p]    = keep ? dist : 0.0f;
                out[3l*P+p*3]   = keep ? dx : 0.0f;
                out[3l*P+p*3+1] = keep ? dy : 0.0f;
                out[3l*P+p*3+2] = keep ? dz : 0.0f;
            }
        }
    }
}

extern "C" void kernel_launch(void* const* d_in, const int* in_sizes, int n_in,
                              void* d_out, int out_size, void* d_ws, size_t ws_size,
                              hipStream_t stream) {
    const int*   species = (const int*)  d_in[0];   // (1, N) int32
    const float* coords  = (const float*)d_in[1];   // (1, N, 3) f32
    const int*   nbr     = (const int*)  d_in[2];   // (2, P) int32
    const float* shift   = (const float*)d_in[3];   // (P, 3) f32
    float* out = (float*)d_out;                     // 6*P floats

    const int N = in_sizes[0];
    const int P = in_sizes[2] / 2;

    f32x4* atoms = (f32x4*)d_ws;
    hipLaunchKernelGGL(pack_atoms_kernel, dim3((N + BLOCK - 1) / BLOCK),
                       dim3(BLOCK), 0, stream, species, coords, atoms, N);

    const int nTiles = (P + BP - 1) / BP;
    // persistent grid: 4 blocks/CU (VGPR-limited waves) x 256 CUs, capped by tiles
    int grid = 1024;
    if (grid > nTiles) grid = nTiles;
    hipLaunchKernelGGL(nbr_screen_pipe_kernel, dim3(grid), dim3(BLOCK), 0,
                       stream, atoms, nbr, shift, out, P);
}